// Round 2
// baseline (100.235 us; speedup 1.0000x reference)
//
#include <hip/hip_runtime.h>
#include <hip/hip_bf16.h>
#include <math.h>

#define NV 32
#define E  16
#define FF 64
#define BATCH 32768
#define L2E 1.4426950408889634f

static constexpr float EPS = 1e-5f;

typedef __attribute__((ext_vector_type(8)))  short bf16x8;
typedef __attribute__((ext_vector_type(16))) float f32x16;
typedef __attribute__((ext_vector_type(4)))  unsigned u32x4;

#define LD4(p) (*reinterpret_cast<const float4*>(p))

__device__ __forceinline__ short f2bf(float f) {
    __hip_bfloat16 h = __float2bfloat16(f);
    return __builtin_bit_cast(short, h);
}
__device__ __forceinline__ unsigned pack2(float a, float b) {
    return (unsigned)(unsigned short)f2bf(a) | ((unsigned)(unsigned short)f2bf(b) << 16);
}
// Half exchange via gfx950 v_permlane32_swap: a' = {a.lo, b.lo}, b' = {a.hi, b.hi}
__device__ __forceinline__ void halfswap(unsigned &a, unsigned &b) {
    const auto r = __builtin_amdgcn_permlane32_swap(a, b, false, false);
    a = (unsigned)r[0]; b = (unsigned)r[1];
}
// cross-half sum: r[0]+r[1] == own + partner on BOTH halves (no select needed)
__device__ __forceinline__ float addxhalf(float v) {
    const unsigned u = __builtin_bit_cast(unsigned, v);
    const auto r = __builtin_amdgcn_permlane32_swap(u, u, false, false);
    return __builtin_bit_cast(float, (unsigned)r[0]) + __builtin_bit_cast(float, (unsigned)r[1]);
}
// DPP row-rotate add (full-rate VALU, no LDS pipe)
template <int CTRL>
__device__ __forceinline__ float dpp_add(float v) {
    const int s = __builtin_amdgcn_update_dpp(0, __builtin_bit_cast(int, v), CTRL, 0xF, 0xF, true);
    return v + __builtin_bit_cast(float, s);
}
// sum over each 32-lane group (rows via DPP ror 1/2/4/8, cross-row via xor16)
__device__ __forceinline__ float sum32(float v) {
    v = dpp_add<0x121>(v);   // row_ror:1
    v = dpp_add<0x122>(v);   // row_ror:2
    v = dpp_add<0x124>(v);   // row_ror:4
    v = dpp_add<0x128>(v);   // row_ror:8
    return v + __shfl_xor(v, 16);
}
// canonical feature permutation: lane-half h, slot i -> feature index
__device__ __forceinline__ int psi(int h, int i) {
    return 4 * h + (i & 3) + 8 * (i >> 2);
}
__device__ __forceinline__ float ex2(float x) { return __builtin_amdgcn_exp2f(x); }
// gelu tanh-approx with log2e folded into the polynomial (exp2-domain)
__device__ __forceinline__ float gelu_fast(float x) {
    const float x2 = x * x;
    const float u  = x * fmaf(x2, 0.10294324f, 2.3022082f);
    return x - x * __builtin_amdgcn_rcpf(1.0f + ex2(u));
}
__device__ __forceinline__ bf16x8 pack8(const float* v) {
    bf16x8 r;
#pragma unroll
    for (int i = 0; i < 8; i++) r[i] = f2bf(v[i]);
    return r;
}
__device__ __forceinline__ float dot16(const float* __restrict__ wrow, const float* __restrict__ v) {
    float s = 0.f;
#pragma unroll
    for (int j = 0; j < 4; j++) {
        const float4 a = LD4(wrow + 4 * j);
        const float4 c = LD4(v + 4 * j);
        s = fmaf(a.x, c.x, fmaf(a.y, c.y, fmaf(a.z, c.z, fmaf(a.w, c.w, s))));
    }
    return s;
}

__global__ __launch_bounds__(256, 8) void event_classifier_kernel(
    const float* __restrict__ x,
    const float* __restrict__ emb_w1,    // (NV, 4)
    const float* __restrict__ emb_b1,    // (NV, 4)
    const float* __restrict__ emb_w2,    // (NV, 4, 16)
    const float* __restrict__ emb_b2,    // (NV, 16)
    const float* __restrict__ ln1_g, const float* __restrict__ ln1_b,
    const float* __restrict__ attn_wi,   // (48, 16)
    const float* __restrict__ attn_bi,   // (48)
    const float* __restrict__ attn_wo,   // (16, 16)
    const float* __restrict__ attn_bo,   // (16)
    const float* __restrict__ ln2_g, const float* __restrict__ ln2_b,
    const float* __restrict__ fc1_w,     // (64, 16)
    const float* __restrict__ fc1_b,     // (64)
    const float* __restrict__ fc2_w,     // (16, 64)
    const float* __restrict__ fc2_b,     // (16)
    const float* __restrict__ cls_token, // (16)
    const float* __restrict__ cln1_g, const float* __restrict__ cln1_b,
    const float* __restrict__ cattn_wi,  // (48, 16)
    const float* __restrict__ cattn_bi,  // (48)
    const float* __restrict__ cattn_wo,  // (16, 16)
    const float* __restrict__ cattn_bo,  // (16)
    const float* __restrict__ cln2_g, const float* __restrict__ cln2_b,
    const float* __restrict__ clsfc_w,   // (1, 16)
    const float* __restrict__ clsfc_b,   // (1)
    float* __restrict__ out)             // (B, 1)
{
    // ---- LDS (~18.9 KB) ----
    __shared__ alignas(16) unsigned s_frag[11][64][4];          // 11,264 B
    __shared__ alignas(16) float s_bias[8][32];                 //  1,024 B
    __shared__ alignas(16) unsigned short s_vt[4][4][5][40];    //  6,400 B  V^T bf16 (+ones row 4), stride 40
    __shared__ alignas(16) float s_cls[48];                     //    192 B
    __shared__ alignas(16) float s_cw[20];                      //     80 B  cln2_g*clsfc_w + folded bias

    const int tid = threadIdx.x;
    const int l   = tid & 63;
    const int t   = l & 31;        // token
    const int hh  = l >> 5;        // lane-half
    const int w   = tid >> 6;      // wave = event slot
    const int b   = blockIdx.x * 4 + w;

    // ---- stage weight A-fragments (LN gammas folded into columns):
    // f: 0=Wq(*0.5*log2e,rows0-15)+Wk(rows16-31)  1=Wv  2=Wo  3,4=fc1a/b  5..8=fc2 k-chunks
    //    9=cWk(rows0-15)+cWv(rows16-31)  10=cWo
    // psi(h,0..3)=4h..4h+3 and psi(h,4..7)=4h+8..4h+11 are contiguous -> float4 loads
    for (int f0 = 0; f0 < 12; f0 += 4) {
        const int f = f0 + w;                 // wave-uniform frag index
        if (f < 11) {
            const float* W; const float* gc = nullptr;
            int stride = 16, coff = 0; bool valid = true; float rscale = 1.0f;
            switch (f) {
                case 0:  W = attn_wi;        gc = ln1_g; if (t < 16) rscale = 0.5f * L2E; break;
                case 1:  W = attn_wi + 512;  gc = ln1_g; valid = (t < 16); break;
                case 2:  W = attn_wo;        valid = (t < 16); break;
                case 3:  W = fc1_w;          gc = ln2_g; break;
                case 4:  W = fc1_w + 512;    gc = ln2_g; break;
                case 5: case 6: case 7: case 8:
                         W = fc2_w; stride = 64; coff = (f - 5) * 16; valid = (t < 16); break;
                case 9:  W = cattn_wi + 256; gc = cln1_g; break;   // rows 16-47 = cWk,cWv
                default: W = cattn_wo;       valid = (t < 16); break;
            }
            unsigned d[4] = {0u, 0u, 0u, 0u};
            if (valid) {
                const float* row = W + t * stride + coff + 4 * hh;
                float4 r0 = LD4(row);        // cols psi(hh,0..3)
                float4 r1 = LD4(row + 8);    // cols psi(hh,4..7)
                if (gc) {
                    const float4 g0 = LD4(gc + 4 * hh);
                    const float4 g1 = LD4(gc + 8 + 4 * hh);
                    r0.x *= g0.x; r0.y *= g0.y; r0.z *= g0.z; r0.w *= g0.w;
                    r1.x *= g1.x; r1.y *= g1.y; r1.z *= g1.z; r1.w *= g1.w;
                }
                r0.x *= rscale; r0.y *= rscale; r0.z *= rscale; r0.w *= rscale;
                r1.x *= rscale; r1.y *= rscale; r1.z *= rscale; r1.w *= rscale;
                d[0] = pack2(r0.x, r0.y); d[1] = pack2(r0.z, r0.w);
                d[2] = pack2(r1.x, r1.y); d[3] = pack2(r1.z, r1.w);
            }
            s_frag[f][l][0] = d[0]; s_frag[f][l][1] = d[1];
            s_frag[f][l][2] = d[2]; s_frag[f][l][3] = d[3];
        }
    }
    // ---- stage canonical biases (LN betas folded: b' = b + W*ln_b): s_bias[mat][h*16+r]
    // mat: 0=QK(16: q|k) 1=V 2=attn_bo 3,4=fc1a/b(16) 5=fc2_b 6=cKV(16: k|v) 7=cattn_bo+cls
    {
        const int i = tid;                   // 8*32 == blockDim
        const int mat = i >> 5, idx = i & 31, h2 = idx >> 4, r = idx & 15;
        const int p8 = psi(h2, r & 7);
        float val = 0.f;
        switch (mat) {
            case 0:
                if (r < 8) val = (attn_bi[p8] + dot16(attn_wi + p8 * 16, ln1_b)) * (0.5f * L2E);
                else       val =  attn_bi[16 + p8] + dot16(attn_wi + (16 + p8) * 16, ln1_b);
                break;
            case 1: if (r < 8) val = attn_bi[32 + p8] + dot16(attn_wi + (32 + p8) * 16, ln1_b); break;
            case 2: if (r < 8) val = attn_bo[p8]; break;
            case 3: { const int p16 = psi(h2, r); val = fc1_b[p16] + dot16(fc1_w + p16 * 16, ln2_b); } break;
            case 4: { const int p16 = psi(h2, r); val = fc1_b[32 + p16] + dot16(fc1_w + (32 + p16) * 16, ln2_b); } break;
            case 5: if (r < 8) val = fc2_b[p8]; break;
            case 6:
                if (r < 8) val = cattn_bi[16 + p8] + dot16(cattn_wi + (16 + p8) * 16, cln1_b);
                else       val = cattn_bi[32 + p8] + dot16(cattn_wi + (32 + p8) * 16, cln1_b);
                break;
            default: if (r < 8) val = cattn_bo[p8] + cls_token[p8]; break;
        }
        s_bias[mat][idx] = val;
    }
    // ---- cls-derived constants (q folded *0.5*log2e) + cln2/classifier fold ----
    if (tid < 16) {
        const int jp = tid;
        float cls[E];
        float m = 0.f;
#pragma unroll
        for (int j = 0; j < E; j++) { cls[j] = cls_token[j]; m += cls[j]; }
        m *= (1.0f / E);
        float var = 0.f;
#pragma unroll
        for (int j = 0; j < E; j++) { float d = cls[j] - m; var += d * d; }
        var *= (1.0f / E);
        float r = rsqrtf(var + EPS);
        float un0[E];
#pragma unroll
        for (int j = 0; j < E; j++) un0[j] = (cls[j] - m) * r * cln1_g[j] + cln1_b[j];
        float qq = cattn_bi[jp], kk = cattn_bi[16 + jp], vv2 = cattn_bi[32 + jp];
#pragma unroll
        for (int j = 0; j < E; j++) {
            qq  += cls[j] * cattn_wi[jp * E + j];
            kk  += un0[j] * cattn_wi[(16 + jp) * E + j];
            vv2 += un0[j] * cattn_wi[(32 + jp) * E + j];
        }
        s_cls[jp] = qq * (0.5f * L2E); s_cls[16 + jp] = kk; s_cls[32 + jp] = vv2;
        s_cw[jp] = cln2_g[jp] * clsfc_w[jp];
        if (jp == 0) {
            float s = clsfc_b[0];
#pragma unroll
            for (int j = 0; j < E; j++) s = fmaf(cln2_b[j], clsfc_w[j], s);
            s_cw[16] = s;
        }
    }
    __syncthreads();

#define FRAG(f) (*reinterpret_cast<const bf16x8*>(&s_frag[f][l][0]))
#define CBIAS8(mat, c) { const float4 lo_ = LD4(&s_bias[mat][hh*16]); \
                         const float4 hi_ = LD4(&s_bias[mat][hh*16+4]); \
                         c[0]=lo_.x; c[1]=lo_.y; c[2]=lo_.z; c[3]=lo_.w; \
                         c[4]=hi_.x; c[5]=hi_.y; c[6]=hi_.z; c[7]=hi_.w; \
                         c[8]=0;c[9]=0;c[10]=0;c[11]=0;c[12]=0;c[13]=0;c[14]=0;c[15]=0; }
#define CBIAS16(mat, c) { const float4 a_ = LD4(&s_bias[mat][hh*16]); \
                          const float4 b_ = LD4(&s_bias[mat][hh*16+4]); \
                          const float4 c_ = LD4(&s_bias[mat][hh*16+8]); \
                          const float4 d_ = LD4(&s_bias[mat][hh*16+12]); \
                          c[0]=a_.x;c[1]=a_.y;c[2]=a_.z;c[3]=a_.w; \
                          c[4]=b_.x;c[5]=b_.y;c[6]=b_.z;c[7]=b_.w; \
                          c[8]=c_.x;c[9]=c_.y;c[10]=c_.z;c[11]=c_.w; \
                          c[12]=d_.x;c[13]=d_.y;c[14]=d_.z;c[15]=d_.w; }

    f32x16 z16;
#pragma unroll
    for (int i = 0; i < 16; i++) z16[i] = 0.0f;

    // ---- tokenizer (canonical layout: F[r] = feature psi(hh,r) of token t) ----
    const float xv = x[b * NV + t];
    float F[8];
    {
        const float4 w1 = LD4(emb_w1 + t * 4);
        const float4 b1 = LD4(emb_b1 + t * 4);
        float hb[4];
        hb[0] = gelu_fast(fmaf(xv, w1.x, b1.x));
        hb[1] = gelu_fast(fmaf(xv, w1.y, b1.y));
        hb[2] = gelu_fast(fmaf(xv, w1.z, b1.z));
        hb[3] = gelu_fast(fmaf(xv, w1.w, b1.w));
        float a[8];
        const float4 bA = LD4(emb_b2 + t * 16 + 4 * hh);
        const float4 bB = LD4(emb_b2 + t * 16 + 8 + 4 * hh);
        a[0]=bA.x; a[1]=bA.y; a[2]=bA.z; a[3]=bA.w;
        a[4]=bB.x; a[5]=bB.y; a[6]=bB.z; a[7]=bB.w;
#pragma unroll
        for (int f = 0; f < 4; f++) {
            const float4 wA = LD4(emb_w2 + t * 64 + f * 16 + 4 * hh);
            const float4 wB = LD4(emb_w2 + t * 64 + f * 16 + 8 + 4 * hh);
            a[0] = fmaf(hb[f], wA.x, a[0]); a[1] = fmaf(hb[f], wA.y, a[1]);
            a[2] = fmaf(hb[f], wA.z, a[2]); a[3] = fmaf(hb[f], wA.w, a[3]);
            a[4] = fmaf(hb[f], wB.x, a[4]); a[5] = fmaf(hb[f], wB.y, a[5]);
            a[6] = fmaf(hb[f], wB.z, a[6]); a[7] = fmaf(hb[f], wB.w, a[7]);
        }
#pragma unroll
        for (int r = 0; r < 8; r++) F[r] = gelu_fast(a[r]);
    }

    // plain normalize (gamma/beta folded into consumers' weights/biases)
#define LN_CANON(src, dst) { \
        float s_ = 0.f; \
        _Pragma("unroll") for (int r = 0; r < 8; r++) s_ += src[r]; \
        s_ = addxhalf(s_); \
        const float m_ = s_ * (1.0f / 16.0f); \
        float vs_ = 0.f; \
        _Pragma("unroll") for (int r = 0; r < 8; r++) { float d_ = src[r] - m_; vs_ = fmaf(d_, d_, vs_); } \
        vs_ = addxhalf(vs_); \
        const float rs_ = rsqrtf(vs_ * (1.0f / 16.0f) + EPS); \
        const float nm_ = -m_ * rs_; \
        _Pragma("unroll") for (int r = 0; r < 8; r++) dst[r] = fmaf(src[r], rs_, nm_); }

    // ================= encoder =================
    float res[8];
#pragma unroll
    for (int r = 0; r < 8; r++) res[r] = F[r];
    float tn[8];
    LN_CANON(F, tn);

    const bf16x8 bt = pack8(tn);
    f32x16 cqk, cv;
    CBIAS16(0, cqk); CBIAS8(1, cv);
    // merged MFMA: regs 0-7 = Q (pre-scaled by 0.5*log2e), regs 8-15 = K
    const f32x16 dqk = __builtin_amdgcn_mfma_f32_32x32x16_bf16(FRAG(0), bt, cqk, 0, 0, 0);
    const f32x16 dv  = __builtin_amdgcn_mfma_f32_32x32x16_bf16(FRAG(1), bt, cv, 0, 0, 0);

    // ---- build per-head Q/K score fragments: one halfswap yields two heads ----
    unsigned qx0 = pack2(dqk[0],  dqk[1]),  qx1 = pack2(dqk[2],  dqk[3]);
    unsigned qx2 = pack2(dqk[4],  dqk[5]),  qx3 = pack2(dqk[6],  dqk[7]);
    unsigned kx0 = pack2(dqk[8],  dqk[9]),  kx1 = pack2(dqk[10], dqk[11]);
    unsigned kx2 = pack2(dqk[12], dqk[13]), kx3 = pack2(dqk[14], dqk[15]);
    halfswap(qx0, qx1); halfswap(qx2, qx3);   // qx0..3 = Q-frag dword0 for heads 0..3
    halfswap(kx0, kx1); halfswap(kx2, kx3);   // kx0..3 = K-frag dword0 for heads 0..3

    // ---- stage V^T in bf16 (+ ones row for denominator) ----
    s_vt[w][hh][0][t] = (unsigned short)f2bf(dv[0]);
    s_vt[w][hh][1][t] = (unsigned short)f2bf(dv[1]);
    s_vt[w][hh][2][t] = (unsigned short)f2bf(dv[2]);
    s_vt[w][hh][3][t] = (unsigned short)f2bf(dv[3]);
    s_vt[w][hh + 2][0][t] = (unsigned short)f2bf(dv[4]);
    s_vt[w][hh + 2][1][t] = (unsigned short)f2bf(dv[5]);
    s_vt[w][hh + 2][2][t] = (unsigned short)f2bf(dv[6]);
    s_vt[w][hh + 2][3][t] = (unsigned short)f2bf(dv[7]);
    s_vt[w][hh][4][t]     = 0x3F80;   // bf16 1.0
    s_vt[w][hh + 2][4][t] = 0x3F80;
    asm volatile("s_waitcnt lgkmcnt(0)" ::: "memory");  // wave-local producer->consumer
    __builtin_amdgcn_sched_barrier(0);

    // ---- per-head: S^T = K*Q^T MFMA -> exp2 -> P^T B-frags -> PV MFMA (V^T|1s) ----
    const int mr = (t < 5) ? t : 0;      // A rows beyond 4 duplicate row 0 (ignored)
    unsigned um0[4], um1[4];
#pragma unroll
    for (int h = 0; h < 4; h++) {
        const unsigned qf = (h == 0) ? qx0 : (h == 1) ? qx1 : (h == 2) ? qx2 : qx3;
        const unsigned kf = (h == 0) ? kx0 : (h == 1) ? kx1 : (h == 2) ? kx2 : kx3;
        const u32x4 au = {kf, 0u, 0u, 0u};
        const u32x4 bu = {qf, 0u, 0u, 0u};
        const f32x16 S = __builtin_amdgcn_mfma_f32_32x32x16_bf16(
            __builtin_bit_cast(bf16x8, au), __builtin_bit_cast(bf16x8, bu), z16, 0, 0, 0);
        unsigned w0 = pack2(ex2(S[0]),  ex2(S[1]));
        unsigned w1 = pack2(ex2(S[2]),  ex2(S[3]));
        unsigned w2 = pack2(ex2(S[4]),  ex2(S[5]));
        unsigned w3 = pack2(ex2(S[6]),  ex2(S[7]));
        unsigned w4 = pack2(ex2(S[8]),  ex2(S[9]));
        unsigned w5 = pack2(ex2(S[10]), ex2(S[11]));
        unsigned w6 = pack2(ex2(S[12]), ex2(S[13]));
        unsigned w7 = pack2(ex2(S[14]), ex2(S[15]));
        halfswap(w0, w2); halfswap(w1, w3);   // B1 = [w0,w1,w2,w3] (k' 0..15)
        halfswap(w4, w6); halfswap(w5, w7);   // B2 = [w4,w5,w6,w7] (k' 16..31)
        const u32x4 b1u = {w0, w1, w2, w3};
        const u32x4 b2u = {w4, w5, w6, w7};
        const bf16x8 A1 = *reinterpret_cast<const bf16x8*>(&s_vt[w][h][mr][8 * hh]);
        const bf16x8 A2 = *reinterpret_cast<const bf16x8*>(&s_vt[w][h][mr][8 * hh + 16]);
        f32x16 R = __builtin_amdgcn_mfma_f32_32x32x16_bf16(A1, __builtin_bit_cast(bf16x8, b1u), z16, 0, 0, 0);
        R = __builtin_amdgcn_mfma_f32_32x32x16_bf16(A2, __builtin_bit_cast(bf16x8, b2u), R, 0, 0, 0);
        // denominator L: permlane32_swap(R0,R0)[1] == L[q] on BOTH halves -> no guard.
        const unsigned ru = __builtin_bit_cast(unsigned, R[0]);
        const auto rr = __builtin_amdgcn_permlane32_swap(ru, ru, false, false);
        const float rl = __builtin_amdgcn_rcpf(__builtin_bit_cast(float, (unsigned)rr[1]));
        um0[h] = pack2(R[0] * rl, R[1] * rl);
        um1[h] = pack2(R[2] * rl, R[3] * rl);
    }
    // merge heads into out-proj B-operand: lower lanes heads 0,2; upper heads 1,3
    halfswap(um0[0], um0[1]); halfswap(um1[0], um1[1]);
    halfswap(um0[2], um0[3]); halfswap(um1[2], um1[3]);
    const u32x4 bou = {um0[0], um1[0], um0[2], um1[2]};
    const bf16x8 bo = __builtin_bit_cast(bf16x8, bou);

    // out-projection + residual
    {
        f32x16 co; CBIAS8(2, co);
        const f32x16 dto = __builtin_amdgcn_mfma_f32_32x32x16_bf16(FRAG(2), bo, co, 0, 0, 0);
#pragma unroll
        for (int r = 0; r < 8; r++) F[r] = dto[r] + res[r];
    }

    // ---- FFN ----
#pragma unroll
    for (int r = 0; r < 8; r++) res[r] = F[r];
    float tn2[8];
    LN_CANON(F, tn2);
    {
        const bf16x8 bt2 = pack8(tn2);
        f32x16 c1, c2;
        CBIAS16(3, c1); CBIAS16(4, c2);
        const f32x16 g1 = __builtin_amdgcn_mfma_f32_32x32x16_bf16(FRAG(3), bt2, c1, 0, 0, 0);
        const f32x16 g2 = __builtin_amdgcn_mfma_f32_32x32x16_bf16(FRAG(4), bt2, c2, 0, 0, 0);
        float gva[16], gvb[16];
#pragma unroll
        for (int r = 0; r < 16; r++) gva[r] = gelu_fast(g1[r]);
#pragma unroll
        for (int r = 0; r < 16; r++) gvb[r] = gelu_fast(g2[r]);
        const bf16x8 pk0 = pack8(gva), pk1 = pack8(gva + 8);
        const bf16x8 pk2 = pack8(gvb), pk3 = pack8(gvb + 8);
        f32x16 acc; CBIAS8(5, acc);
        acc = __builtin_amdgcn_mfma_f32_32x32x16_bf16(FRAG(5), pk0, acc, 0, 0, 0);
        acc = __builtin_amdgcn_mfma_f32_32x32x16_bf16(FRAG(6), pk1, acc, 0, 0, 0);
        acc = __builtin_amdgcn_mfma_f32_32x32x16_bf16(FRAG(7), pk2, acc, 0, 0, 0);
        acc = __builtin_amdgcn_mfma_f32_32x32x16_bf16(FRAG(8), pk3, acc, 0, 0, 0);
#pragma unroll
        for (int r = 0; r < 8; r++) F[r] = acc[r] + res[r];
    }

    // ================= class-token decoder =================
    float tn3[8];
    LN_CANON(F, tn3);
    const bf16x8 bt3 = pack8(tn3);
    f32x16 ckv; CBIAS16(6, ckv);
    // merged MFMA: regs 0-7 = K_c, regs 8-15 = V_c
    const f32x16 dkv = __builtin_amdgcn_mfma_f32_32x32x16_bf16(FRAG(9), bt3, ckv, 0, 0, 0);

    const float4 qcA = LD4(s_cls + 4 * hh);
    const float4 qcB = LD4(s_cls + 8 + 4 * hh);
    const float sA2 = fmaf(qcA.x, dkv[0], fmaf(qcA.y, dkv[1], fmaf(qcA.z, dkv[2], qcA.w * dkv[3])));
    const float sB2 = fmaf(qcB.x, dkv[4], fmaf(qcB.y, dkv[5], fmaf(qcB.z, dkv[6], qcB.w * dkv[7])));
    const float pA2 = ex2(sA2), pB2 = ex2(sB2);
    const float4 k0A = LD4(s_cls + 16 + 4 * hh);
    const float4 k0B = LD4(s_cls + 16 + 8 + 4 * hh);
    const float s0A = fmaf(qcA.x, k0A.x, fmaf(qcA.y, k0A.y, fmaf(qcA.z, k0A.z, qcA.w * k0A.w)));
    const float s0B = fmaf(qcB.x, k0B.x, fmaf(qcB.y, k0B.y, fmaf(qcB.z, k0B.z, qcB.w * k0B.w)));
    const float p0A = ex2(s0A), p0B = ex2(s0B);

    float lA2 = sum32(pA2), lB2 = sum32(pB2);
    float oc[8];
    oc[0] = sum32(pA2 * dkv[8]);  oc[1] = sum32(pA2 * dkv[9]);
    oc[2] = sum32(pA2 * dkv[10]); oc[3] = sum32(pA2 * dkv[11]);
    oc[4] = sum32(pB2 * dkv[12]); oc[5] = sum32(pB2 * dkv[13]);
    oc[6] = sum32(pB2 * dkv[14]); oc[7] = sum32(pB2 * dkv[15]);
    {
        const float4 v0A = LD4(s_cls + 32 + 4 * hh);
        const float4 v0B = LD4(s_cls + 32 + 8 + 4 * hh);
        const float rA2 = __builtin_amdgcn_rcpf(lA2 + p0A);
        const float rB2 = __builtin_amdgcn_rcpf(lB2 + p0B);
        oc[0] = (oc[0] + p0A * v0A.x) * rA2; oc[1] = (oc[1] + p0A * v0A.y) * rA2;
        oc[2] = (oc[2] + p0A * v0A.z) * rA2; oc[3] = (oc[3] + p0A * v0A.w) * rA2;
        oc[4] = (oc[4] + p0B * v0B.x) * rB2; oc[5] = (oc[5] + p0B * v0B.y) * rB2;
        oc[6] = (oc[6] + p0B * v0B.z) * rB2; oc[7] = (oc[7] + p0B * v0B.w) * rB2;
    }

    // out-projection (+ cattn_bo + cls residual via C), then folded cln2 + classifier
    float c8[8];
    {
        const bf16x8 boc = pack8(oc);
        f32x16 cc; CBIAS8(7, cc);
        const f32x16 dc = __builtin_amdgcn_mfma_f32_32x32x16_bf16(FRAG(10), boc, cc, 0, 0, 0);
#pragma unroll
        for (int r = 0; r < 8; r++) c8[r] = dc[r];
    }
    {
        float s = 0.f;
#pragma unroll
        for (int r = 0; r < 8; r++) s += c8[r];
        s = addxhalf(s);
        const float m = s * (1.0f / 16.0f);
        float vs = 0.f;
#pragma unroll
        for (int r = 0; r < 8; r++) { const float d = c8[r] - m; vs = fmaf(d, d, vs); }
        vs = addxhalf(vs);
        const float rstd = rsqrtf(vs * (1.0f / 16.0f) + EPS);
        const float nm = -m * rstd;
        const float4 wA = LD4(s_cw + 4 * hh), wB = LD4(s_cw + 8 + 4 * hh);
        float zp = 0.f;
        zp = fmaf(fmaf(c8[0], rstd, nm), wA.x, zp);
        zp = fmaf(fmaf(c8[1], rstd, nm), wA.y, zp);
        zp = fmaf(fmaf(c8[2], rstd, nm), wA.z, zp);
        zp = fmaf(fmaf(c8[3], rstd, nm), wA.w, zp);
        zp = fmaf(fmaf(c8[4], rstd, nm), wB.x, zp);
        zp = fmaf(fmaf(c8[5], rstd, nm), wB.y, zp);
        zp = fmaf(fmaf(c8[6], rstd, nm), wB.z, zp);
        zp = fmaf(fmaf(c8[7], rstd, nm), wB.w, zp);
        const float z = addxhalf(zp) + s_cw[16];
        const float sig = __builtin_amdgcn_rcpf(1.0f + ex2(-L2E * z));
        if (l == 0) out[b] = sig;
    }
}

extern "C" void kernel_launch(void* const* d_in, const int* in_sizes, int n_in,
                              void* d_out, int out_size, void* d_ws, size_t ws_size,
                              hipStream_t stream) {
    const float* x        = (const float*)d_in[0];
    const float* emb_w1   = (const float*)d_in[1];
    const float* emb_b1   = (const float*)d_in[2];
    const float* emb_w2   = (const float*)d_in[3];
    const float* emb_b2   = (const float*)d_in[4];
    const float* ln1_g    = (const float*)d_in[5];
    const float* ln1_b    = (const float*)d_in[6];
    const float* attn_wi  = (const float*)d_in[7];
    const float* attn_bi  = (const float*)d_in[8];
    const float* attn_wo  = (const float*)d_in[9];
    const float* attn_bo  = (const float*)d_in[10];
    const float* ln2_g    = (const float*)d_in[11];
    const float* ln2_b    = (const float*)d_in[12];
    const float* fc1_w    = (const float*)d_in[13];
    const float* fc1_b    = (const float*)d_in[14];
    const float* fc2_w    = (const float*)d_in[15];
    const float* fc2_b    = (const float*)d_in[16];
    const float* cls_tok  = (const float*)d_in[17];
    const float* cln1_g   = (const float*)d_in[18];
    const float* cln1_b   = (const float*)d_in[19];
    const float* cattn_wi = (const float*)d_in[20];
    const float* cattn_bi = (const float*)d_in[21];
    const float* cattn_wo = (const float*)d_in[22];
    const float* cattn_bo = (const float*)d_in[23];
    const float* cln2_g   = (const float*)d_in[24];
    const float* cln2_b   = (const float*)d_in[25];
    const float* clsfc_w  = (const float*)d_in[26];
    const float* clsfc_b  = (const float*)d_in[27];
    float* out = (float*)d_out;

    const int grid = BATCH / 4;   // 1 event per wave, 4 waves per block
    event_classifier_kernel<<<grid, 256, 0, stream>>>(
        x, emb_w1, emb_b1, emb_w2, emb_b2, ln1_g, ln1_b,
        attn_wi, attn_bi, attn_wo, attn_bo, ln2_g, ln2_b,
        fc1_w, fc1_b, fc2_w, fc2_b, cls_tok,
        cln1_g, cln1_b, cattn_wi, cattn_bi, cattn_wo, cattn_bo,
        cln2_g, cln2_b, clsfc_w, clsfc_b, out);
}

// Round 3
// 92.514 us; speedup vs baseline: 1.0835x; 1.0835x over previous
//
#include <hip/hip_runtime.h>
#include <hip/hip_bf16.h>
#include <math.h>

#define NV 32
#define E  16
#define FF 64
#define BATCH 32768
#define L2E 1.4426950408889634f

static constexpr float EPS = 1e-5f;

typedef __attribute__((ext_vector_type(8)))  short bf16x8;
typedef __attribute__((ext_vector_type(16))) float f32x16;
typedef __attribute__((ext_vector_type(4)))  unsigned u32x4;

#define LD4(p) (*reinterpret_cast<const float4*>(p))

__device__ __forceinline__ short f2bf(float f) {
    __hip_bfloat16 h = __float2bfloat16(f);
    return __builtin_bit_cast(short, h);
}
__device__ __forceinline__ unsigned pack2(float a, float b) {
    return (unsigned)(unsigned short)f2bf(a) | ((unsigned)(unsigned short)f2bf(b) << 16);
}
// Half exchange via gfx950 v_permlane32_swap: a' = {a.lo, b.lo}, b' = {a.hi, b.hi}
__device__ __forceinline__ void halfswap(unsigned &a, unsigned &b) {
    const auto r = __builtin_amdgcn_permlane32_swap(a, b, false, false);
    a = (unsigned)r[0]; b = (unsigned)r[1];
}
// cross-half sum: r[0]+r[1] == own + partner on BOTH halves (no select needed)
__device__ __forceinline__ float addxhalf(float v) {
    const unsigned u = __builtin_bit_cast(unsigned, v);
    const auto r = __builtin_amdgcn_permlane32_swap(u, u, false, false);
    return __builtin_bit_cast(float, (unsigned)r[0]) + __builtin_bit_cast(float, (unsigned)r[1]);
}
// DPP row-rotate add (full-rate VALU, no LDS pipe)
template <int CTRL>
__device__ __forceinline__ float dpp_add(float v) {
    const int s = __builtin_amdgcn_update_dpp(0, __builtin_bit_cast(int, v), CTRL, 0xF, 0xF, true);
    return v + __builtin_bit_cast(float, s);
}
// sum over each 32-lane group (rows via DPP ror 1/2/4/8, cross-row via xor16)
__device__ __forceinline__ float sum32(float v) {
    v = dpp_add<0x121>(v);   // row_ror:1
    v = dpp_add<0x122>(v);   // row_ror:2
    v = dpp_add<0x124>(v);   // row_ror:4
    v = dpp_add<0x128>(v);   // row_ror:8
    return v + __shfl_xor(v, 16);
}
// canonical feature permutation: lane-half h, slot i -> feature index
__device__ __forceinline__ int psi(int h, int i) {
    return 4 * h + (i & 3) + 8 * (i >> 2);
}
__device__ __forceinline__ float ex2(float x) { return __builtin_amdgcn_exp2f(x); }
// gelu tanh-approx with log2e folded into the polynomial (exp2-domain)
__device__ __forceinline__ float gelu_fast(float x) {
    const float x2 = x * x;
    const float u  = x * fmaf(x2, 0.10294324f, 2.3022082f);
    return x - x * __builtin_amdgcn_rcpf(1.0f + ex2(u));
}
__device__ __forceinline__ bf16x8 pack8(const float* v) {
    bf16x8 r;
#pragma unroll
    for (int i = 0; i < 8; i++) r[i] = f2bf(v[i]);
    return r;
}
__device__ __forceinline__ float dot16(const float* __restrict__ wrow, const float* __restrict__ v) {
    float s = 0.f;
#pragma unroll
    for (int j = 0; j < 4; j++) {
        const float4 a = LD4(wrow + 4 * j);
        const float4 c = LD4(v + 4 * j);
        s = fmaf(a.x, c.x, fmaf(a.y, c.y, fmaf(a.z, c.z, fmaf(a.w, c.w, s))));
    }
    return s;
}

__global__ __launch_bounds__(256, 6) void event_classifier_kernel(
    const float* __restrict__ x,
    const float* __restrict__ emb_w1,    // (NV, 4)
    const float* __restrict__ emb_b1,    // (NV, 4)
    const float* __restrict__ emb_w2,    // (NV, 4, 16)
    const float* __restrict__ emb_b2,    // (NV, 16)
    const float* __restrict__ ln1_g, const float* __restrict__ ln1_b,
    const float* __restrict__ attn_wi,   // (48, 16)
    const float* __restrict__ attn_bi,   // (48)
    const float* __restrict__ attn_wo,   // (16, 16)
    const float* __restrict__ attn_bo,   // (16)
    const float* __restrict__ ln2_g, const float* __restrict__ ln2_b,
    const float* __restrict__ fc1_w,     // (64, 16)
    const float* __restrict__ fc1_b,     // (64)
    const float* __restrict__ fc2_w,     // (16, 64)
    const float* __restrict__ fc2_b,     // (16)
    const float* __restrict__ cls_token, // (16)
    const float* __restrict__ cln1_g, const float* __restrict__ cln1_b,
    const float* __restrict__ cattn_wi,  // (48, 16)
    const float* __restrict__ cattn_bi,  // (48)
    const float* __restrict__ cattn_wo,  // (16, 16)
    const float* __restrict__ cattn_bo,  // (16)
    const float* __restrict__ cln2_g, const float* __restrict__ cln2_b,
    const float* __restrict__ clsfc_w,   // (1, 16)
    const float* __restrict__ clsfc_b,   // (1)
    float* __restrict__ out)             // (B, 1)
{
    // ---- LDS (~18.9 KB) ----
    __shared__ alignas(16) unsigned s_frag[11][64][4];          // 11,264 B
    __shared__ alignas(16) float s_bias[8][32];                 //  1,024 B
    __shared__ alignas(16) unsigned short s_vt[4][4][5][40];    //  6,400 B  V^T bf16 (+ones row 4), stride 40
    __shared__ alignas(16) float s_cls[48];                     //    192 B
    __shared__ alignas(16) float s_cw[20];                      //     80 B  cln2_g*clsfc_w + folded bias

    const int tid = threadIdx.x;
    const int l   = tid & 63;
    const int t   = l & 31;        // token
    const int hh  = l >> 5;        // lane-half
    const int w   = tid >> 6;      // wave = event slot
    const int b   = blockIdx.x * 4 + w;

    // ---- stage weight A-fragments (LN gammas folded into columns):
    // f: 0=Wq(*0.5*log2e,rows0-15)+Wk(rows16-31)  1=Wv  2=Wo  3,4=fc1a/b  5..8=fc2 k-chunks
    //    9=cWk(rows0-15)+cWv(rows16-31)  10=cWo
    // psi(h,0..3)=4h..4h+3 and psi(h,4..7)=4h+8..4h+11 are contiguous -> float4 loads
    for (int f0 = 0; f0 < 12; f0 += 4) {
        const int f = f0 + w;                 // wave-uniform frag index
        if (f < 11) {
            const float* W; const float* gc = nullptr;
            int stride = 16, coff = 0; bool valid = true; float rscale = 1.0f;
            switch (f) {
                case 0:  W = attn_wi;        gc = ln1_g; if (t < 16) rscale = 0.5f * L2E; break;
                case 1:  W = attn_wi + 512;  gc = ln1_g; valid = (t < 16); break;
                case 2:  W = attn_wo;        valid = (t < 16); break;
                case 3:  W = fc1_w;          gc = ln2_g; break;
                case 4:  W = fc1_w + 512;    gc = ln2_g; break;
                case 5: case 6: case 7: case 8:
                         W = fc2_w; stride = 64; coff = (f - 5) * 16; valid = (t < 16); break;
                case 9:  W = cattn_wi + 256; gc = cln1_g; break;   // rows 16-47 = cWk,cWv
                default: W = cattn_wo;       valid = (t < 16); break;
            }
            unsigned d[4] = {0u, 0u, 0u, 0u};
            if (valid) {
                const float* row = W + t * stride + coff + 4 * hh;
                float4 r0 = LD4(row);        // cols psi(hh,0..3)
                float4 r1 = LD4(row + 8);    // cols psi(hh,4..7)
                if (gc) {
                    const float4 g0 = LD4(gc + 4 * hh);
                    const float4 g1 = LD4(gc + 8 + 4 * hh);
                    r0.x *= g0.x; r0.y *= g0.y; r0.z *= g0.z; r0.w *= g0.w;
                    r1.x *= g1.x; r1.y *= g1.y; r1.z *= g1.z; r1.w *= g1.w;
                }
                r0.x *= rscale; r0.y *= rscale; r0.z *= rscale; r0.w *= rscale;
                r1.x *= rscale; r1.y *= rscale; r1.z *= rscale; r1.w *= rscale;
                d[0] = pack2(r0.x, r0.y); d[1] = pack2(r0.z, r0.w);
                d[2] = pack2(r1.x, r1.y); d[3] = pack2(r1.z, r1.w);
            }
            s_frag[f][l][0] = d[0]; s_frag[f][l][1] = d[1];
            s_frag[f][l][2] = d[2]; s_frag[f][l][3] = d[3];
        }
    }
    // ---- stage canonical biases (LN betas folded: b' = b + W*ln_b): s_bias[mat][h*16+r]
    // mat: 0=QK(16: q|k) 1=V 2=attn_bo 3,4=fc1a/b(16) 5=fc2_b 6=cKV(16: k|v) 7=cattn_bo+cls
    {
        const int i = tid;                   // 8*32 == blockDim
        const int mat = i >> 5, idx = i & 31, h2 = idx >> 4, r = idx & 15;
        const int p8 = psi(h2, r & 7);
        float val = 0.f;
        switch (mat) {
            case 0:
                if (r < 8) val = (attn_bi[p8] + dot16(attn_wi + p8 * 16, ln1_b)) * (0.5f * L2E);
                else       val =  attn_bi[16 + p8] + dot16(attn_wi + (16 + p8) * 16, ln1_b);
                break;
            case 1: if (r < 8) val = attn_bi[32 + p8] + dot16(attn_wi + (32 + p8) * 16, ln1_b); break;
            case 2: if (r < 8) val = attn_bo[p8]; break;
            case 3: { const int p16 = psi(h2, r); val = fc1_b[p16] + dot16(fc1_w + p16 * 16, ln2_b); } break;
            case 4: { const int p16 = psi(h2, r); val = fc1_b[32 + p16] + dot16(fc1_w + (32 + p16) * 16, ln2_b); } break;
            case 5: if (r < 8) val = fc2_b[p8]; break;
            case 6:
                if (r < 8) val = cattn_bi[16 + p8] + dot16(cattn_wi + (16 + p8) * 16, cln1_b);
                else       val = cattn_bi[32 + p8] + dot16(cattn_wi + (32 + p8) * 16, cln1_b);
                break;
            default: if (r < 8) val = cattn_bo[p8] + cls_token[p8]; break;
        }
        s_bias[mat][idx] = val;
    }
    // ---- cls-derived constants (q folded *0.5*log2e) + cln2/classifier fold ----
    if (tid < 16) {
        const int jp = tid;
        float cls[E];
        float m = 0.f;
#pragma unroll
        for (int j = 0; j < E; j++) { cls[j] = cls_token[j]; m += cls[j]; }
        m *= (1.0f / E);
        float var = 0.f;
#pragma unroll
        for (int j = 0; j < E; j++) { float d = cls[j] - m; var += d * d; }
        var *= (1.0f / E);
        float r = rsqrtf(var + EPS);
        float un0[E];
#pragma unroll
        for (int j = 0; j < E; j++) un0[j] = (cls[j] - m) * r * cln1_g[j] + cln1_b[j];
        float qq = cattn_bi[jp], kk = cattn_bi[16 + jp], vv2 = cattn_bi[32 + jp];
#pragma unroll
        for (int j = 0; j < E; j++) {
            qq  += cls[j] * cattn_wi[jp * E + j];
            kk  += un0[j] * cattn_wi[(16 + jp) * E + j];
            vv2 += un0[j] * cattn_wi[(32 + jp) * E + j];
        }
        s_cls[jp] = qq * (0.5f * L2E); s_cls[16 + jp] = kk; s_cls[32 + jp] = vv2;
        s_cw[jp] = cln2_g[jp] * clsfc_w[jp];
        if (jp == 0) {
            float s = clsfc_b[0];
#pragma unroll
            for (int j = 0; j < E; j++) s = fmaf(cln2_b[j], clsfc_w[j], s);
            s_cw[16] = s;
        }
    }
    __syncthreads();

#define FRAG(f) (*reinterpret_cast<const bf16x8*>(&s_frag[f][l][0]))
#define CBIAS8(mat, c) { const float4 lo_ = LD4(&s_bias[mat][hh*16]); \
                         const float4 hi_ = LD4(&s_bias[mat][hh*16+4]); \
                         c[0]=lo_.x; c[1]=lo_.y; c[2]=lo_.z; c[3]=lo_.w; \
                         c[4]=hi_.x; c[5]=hi_.y; c[6]=hi_.z; c[7]=hi_.w; \
                         c[8]=0;c[9]=0;c[10]=0;c[11]=0;c[12]=0;c[13]=0;c[14]=0;c[15]=0; }
#define CBIAS16(mat, c) { const float4 a_ = LD4(&s_bias[mat][hh*16]); \
                          const float4 b_ = LD4(&s_bias[mat][hh*16+4]); \
                          const float4 c_ = LD4(&s_bias[mat][hh*16+8]); \
                          const float4 d_ = LD4(&s_bias[mat][hh*16+12]); \
                          c[0]=a_.x;c[1]=a_.y;c[2]=a_.z;c[3]=a_.w; \
                          c[4]=b_.x;c[5]=b_.y;c[6]=b_.z;c[7]=b_.w; \
                          c[8]=c_.x;c[9]=c_.y;c[10]=c_.z;c[11]=c_.w; \
                          c[12]=d_.x;c[13]=d_.y;c[14]=d_.z;c[15]=d_.w; }

    f32x16 z16;
#pragma unroll
    for (int i = 0; i < 16; i++) z16[i] = 0.0f;

    // ---- tokenizer (canonical layout: F[r] = feature psi(hh,r) of token t) ----
    const float xv = x[b * NV + t];
    float F[8];
    {
        const float4 w1 = LD4(emb_w1 + t * 4);
        const float4 b1 = LD4(emb_b1 + t * 4);
        float hb[4];
        hb[0] = gelu_fast(fmaf(xv, w1.x, b1.x));
        hb[1] = gelu_fast(fmaf(xv, w1.y, b1.y));
        hb[2] = gelu_fast(fmaf(xv, w1.z, b1.z));
        hb[3] = gelu_fast(fmaf(xv, w1.w, b1.w));
        float a[8];
        const float4 bA = LD4(emb_b2 + t * 16 + 4 * hh);
        const float4 bB = LD4(emb_b2 + t * 16 + 8 + 4 * hh);
        a[0]=bA.x; a[1]=bA.y; a[2]=bA.z; a[3]=bA.w;
        a[4]=bB.x; a[5]=bB.y; a[6]=bB.z; a[7]=bB.w;
#pragma unroll
        for (int f = 0; f < 4; f++) {
            const float4 wA = LD4(emb_w2 + t * 64 + f * 16 + 4 * hh);
            const float4 wB = LD4(emb_w2 + t * 64 + f * 16 + 8 + 4 * hh);
            a[0] = fmaf(hb[f], wA.x, a[0]); a[1] = fmaf(hb[f], wA.y, a[1]);
            a[2] = fmaf(hb[f], wA.z, a[2]); a[3] = fmaf(hb[f], wA.w, a[3]);
            a[4] = fmaf(hb[f], wB.x, a[4]); a[5] = fmaf(hb[f], wB.y, a[5]);
            a[6] = fmaf(hb[f], wB.z, a[6]); a[7] = fmaf(hb[f], wB.w, a[7]);
        }
#pragma unroll
        for (int r = 0; r < 8; r++) F[r] = gelu_fast(a[r]);
    }

    // plain normalize (gamma/beta folded into consumers' weights/biases)
#define LN_CANON(src, dst) { \
        float s_ = 0.f; \
        _Pragma("unroll") for (int r = 0; r < 8; r++) s_ += src[r]; \
        s_ = addxhalf(s_); \
        const float m_ = s_ * (1.0f / 16.0f); \
        float vs_ = 0.f; \
        _Pragma("unroll") for (int r = 0; r < 8; r++) { float d_ = src[r] - m_; vs_ = fmaf(d_, d_, vs_); } \
        vs_ = addxhalf(vs_); \
        const float rs_ = rsqrtf(vs_ * (1.0f / 16.0f) + EPS); \
        const float nm_ = -m_ * rs_; \
        _Pragma("unroll") for (int r = 0; r < 8; r++) dst[r] = fmaf(src[r], rs_, nm_); }

    // ================= encoder =================
    float res[8];
#pragma unroll
    for (int r = 0; r < 8; r++) res[r] = F[r];
    float tn[8];
    LN_CANON(F, tn);

    const bf16x8 bt = pack8(tn);
    f32x16 cqk, cv;
    CBIAS16(0, cqk); CBIAS8(1, cv);
    // merged MFMA: regs 0-7 = Q (pre-scaled by 0.5*log2e), regs 8-15 = K
    const f32x16 dqk = __builtin_amdgcn_mfma_f32_32x32x16_bf16(FRAG(0), bt, cqk, 0, 0, 0);
    const f32x16 dv  = __builtin_amdgcn_mfma_f32_32x32x16_bf16(FRAG(1), bt, cv, 0, 0, 0);

    // ---- build per-head Q/K score fragments: one halfswap yields two heads ----
    unsigned qx0 = pack2(dqk[0],  dqk[1]),  qx1 = pack2(dqk[2],  dqk[3]);
    unsigned qx2 = pack2(dqk[4],  dqk[5]),  qx3 = pack2(dqk[6],  dqk[7]);
    unsigned kx0 = pack2(dqk[8],  dqk[9]),  kx1 = pack2(dqk[10], dqk[11]);
    unsigned kx2 = pack2(dqk[12], dqk[13]), kx3 = pack2(dqk[14], dqk[15]);
    halfswap(qx0, qx1); halfswap(qx2, qx3);   // qx0..3 = Q-frag dword0 for heads 0..3
    halfswap(kx0, kx1); halfswap(kx2, kx3);   // kx0..3 = K-frag dword0 for heads 0..3

    // ---- stage V^T in bf16 (+ ones row for denominator) ----
    s_vt[w][hh][0][t] = (unsigned short)f2bf(dv[0]);
    s_vt[w][hh][1][t] = (unsigned short)f2bf(dv[1]);
    s_vt[w][hh][2][t] = (unsigned short)f2bf(dv[2]);
    s_vt[w][hh][3][t] = (unsigned short)f2bf(dv[3]);
    s_vt[w][hh + 2][0][t] = (unsigned short)f2bf(dv[4]);
    s_vt[w][hh + 2][1][t] = (unsigned short)f2bf(dv[5]);
    s_vt[w][hh + 2][2][t] = (unsigned short)f2bf(dv[6]);
    s_vt[w][hh + 2][3][t] = (unsigned short)f2bf(dv[7]);
    s_vt[w][hh][4][t]     = 0x3F80;   // bf16 1.0
    s_vt[w][hh + 2][4][t] = 0x3F80;
    asm volatile("s_waitcnt lgkmcnt(0)" ::: "memory");  // wave-local producer->consumer
    __builtin_amdgcn_sched_barrier(0);

    // ---- per-head: S^T = K*Q^T MFMA -> exp2 -> P^T B-frags -> PV MFMA (V^T|1s) ----
    const int mr = (t < 5) ? t : 0;      // A rows beyond 4 duplicate row 0 (ignored)
    unsigned um0[4], um1[4];
#pragma unroll
    for (int h = 0; h < 4; h++) {
        const unsigned qf = (h == 0) ? qx0 : (h == 1) ? qx1 : (h == 2) ? qx2 : qx3;
        const unsigned kf = (h == 0) ? kx0 : (h == 1) ? kx1 : (h == 2) ? kx2 : kx3;
        const u32x4 au = {kf, 0u, 0u, 0u};
        const u32x4 bu = {qf, 0u, 0u, 0u};
        const f32x16 S = __builtin_amdgcn_mfma_f32_32x32x16_bf16(
            __builtin_bit_cast(bf16x8, au), __builtin_bit_cast(bf16x8, bu), z16, 0, 0, 0);
        unsigned w0 = pack2(ex2(S[0]),  ex2(S[1]));
        unsigned w1 = pack2(ex2(S[2]),  ex2(S[3]));
        unsigned w2 = pack2(ex2(S[4]),  ex2(S[5]));
        unsigned w3 = pack2(ex2(S[6]),  ex2(S[7]));
        unsigned w4 = pack2(ex2(S[8]),  ex2(S[9]));
        unsigned w5 = pack2(ex2(S[10]), ex2(S[11]));
        unsigned w6 = pack2(ex2(S[12]), ex2(S[13]));
        unsigned w7 = pack2(ex2(S[14]), ex2(S[15]));
        halfswap(w0, w2); halfswap(w1, w3);   // B1 = [w0,w1,w2,w3] (k' 0..15)
        halfswap(w4, w6); halfswap(w5, w7);   // B2 = [w4,w5,w6,w7] (k' 16..31)
        const u32x4 b1u = {w0, w1, w2, w3};
        const u32x4 b2u = {w4, w5, w6, w7};
        const bf16x8 A1 = *reinterpret_cast<const bf16x8*>(&s_vt[w][h][mr][8 * hh]);
        const bf16x8 A2 = *reinterpret_cast<const bf16x8*>(&s_vt[w][h][mr][8 * hh + 16]);
        f32x16 R = __builtin_amdgcn_mfma_f32_32x32x16_bf16(A1, __builtin_bit_cast(bf16x8, b1u), z16, 0, 0, 0);
        R = __builtin_amdgcn_mfma_f32_32x32x16_bf16(A2, __builtin_bit_cast(bf16x8, b2u), R, 0, 0, 0);
        // denominator L: permlane32_swap(R0,R0)[1] == L[q] on BOTH halves -> no guard.
        const unsigned ru = __builtin_bit_cast(unsigned, R[0]);
        const auto rr = __builtin_amdgcn_permlane32_swap(ru, ru, false, false);
        const float rl = __builtin_amdgcn_rcpf(__builtin_bit_cast(float, (unsigned)rr[1]));
        um0[h] = pack2(R[0] * rl, R[1] * rl);
        um1[h] = pack2(R[2] * rl, R[3] * rl);
    }
    // merge heads into out-proj B-operand: lower lanes heads 0,2; upper heads 1,3
    halfswap(um0[0], um0[1]); halfswap(um1[0], um1[1]);
    halfswap(um0[2], um0[3]); halfswap(um1[2], um1[3]);
    const u32x4 bou = {um0[0], um1[0], um0[2], um1[2]};
    const bf16x8 bo = __builtin_bit_cast(bf16x8, bou);

    // out-projection + residual
    {
        f32x16 co; CBIAS8(2, co);
        const f32x16 dto = __builtin_amdgcn_mfma_f32_32x32x16_bf16(FRAG(2), bo, co, 0, 0, 0);
#pragma unroll
        for (int r = 0; r < 8; r++) F[r] = dto[r] + res[r];
    }

    // ---- FFN ----
#pragma unroll
    for (int r = 0; r < 8; r++) res[r] = F[r];
    float tn2[8];
    LN_CANON(F, tn2);
    {
        const bf16x8 bt2 = pack8(tn2);
        f32x16 c1, c2;
        CBIAS16(3, c1); CBIAS16(4, c2);
        const f32x16 g1 = __builtin_amdgcn_mfma_f32_32x32x16_bf16(FRAG(3), bt2, c1, 0, 0, 0);
        const f32x16 g2 = __builtin_amdgcn_mfma_f32_32x32x16_bf16(FRAG(4), bt2, c2, 0, 0, 0);
        float gva[16], gvb[16];
#pragma unroll
        for (int r = 0; r < 16; r++) gva[r] = gelu_fast(g1[r]);
#pragma unroll
        for (int r = 0; r < 16; r++) gvb[r] = gelu_fast(g2[r]);
        const bf16x8 pk0 = pack8(gva), pk1 = pack8(gva + 8);
        const bf16x8 pk2 = pack8(gvb), pk3 = pack8(gvb + 8);
        f32x16 acc; CBIAS8(5, acc);
        acc = __builtin_amdgcn_mfma_f32_32x32x16_bf16(FRAG(5), pk0, acc, 0, 0, 0);
        acc = __builtin_amdgcn_mfma_f32_32x32x16_bf16(FRAG(6), pk1, acc, 0, 0, 0);
        acc = __builtin_amdgcn_mfma_f32_32x32x16_bf16(FRAG(7), pk2, acc, 0, 0, 0);
        acc = __builtin_amdgcn_mfma_f32_32x32x16_bf16(FRAG(8), pk3, acc, 0, 0, 0);
#pragma unroll
        for (int r = 0; r < 8; r++) F[r] = acc[r] + res[r];
    }

    // ================= class-token decoder =================
    float tn3[8];
    LN_CANON(F, tn3);
    const bf16x8 bt3 = pack8(tn3);
    f32x16 ckv; CBIAS16(6, ckv);
    // merged MFMA: regs 0-7 = K_c, regs 8-15 = V_c
    const f32x16 dkv = __builtin_amdgcn_mfma_f32_32x32x16_bf16(FRAG(9), bt3, ckv, 0, 0, 0);

    const float4 qcA = LD4(s_cls + 4 * hh);
    const float4 qcB = LD4(s_cls + 8 + 4 * hh);
    const float sA2 = fmaf(qcA.x, dkv[0], fmaf(qcA.y, dkv[1], fmaf(qcA.z, dkv[2], qcA.w * dkv[3])));
    const float sB2 = fmaf(qcB.x, dkv[4], fmaf(qcB.y, dkv[5], fmaf(qcB.z, dkv[6], qcB.w * dkv[7])));
    const float pA2 = ex2(sA2), pB2 = ex2(sB2);
    const float4 k0A = LD4(s_cls + 16 + 4 * hh);
    const float4 k0B = LD4(s_cls + 16 + 8 + 4 * hh);
    const float s0A = fmaf(qcA.x, k0A.x, fmaf(qcA.y, k0A.y, fmaf(qcA.z, k0A.z, qcA.w * k0A.w)));
    const float s0B = fmaf(qcB.x, k0B.x, fmaf(qcB.y, k0B.y, fmaf(qcB.z, k0B.z, qcB.w * k0B.w)));
    const float p0A = ex2(s0A), p0B = ex2(s0B);

    float lA2 = sum32(pA2), lB2 = sum32(pB2);
    float oc[8];
    oc[0] = sum32(pA2 * dkv[8]);  oc[1] = sum32(pA2 * dkv[9]);
    oc[2] = sum32(pA2 * dkv[10]); oc[3] = sum32(pA2 * dkv[11]);
    oc[4] = sum32(pB2 * dkv[12]); oc[5] = sum32(pB2 * dkv[13]);
    oc[6] = sum32(pB2 * dkv[14]); oc[7] = sum32(pB2 * dkv[15]);
    {
        const float4 v0A = LD4(s_cls + 32 + 4 * hh);
        const float4 v0B = LD4(s_cls + 32 + 8 + 4 * hh);
        const float rA2 = __builtin_amdgcn_rcpf(lA2 + p0A);
        const float rB2 = __builtin_amdgcn_rcpf(lB2 + p0B);
        oc[0] = (oc[0] + p0A * v0A.x) * rA2; oc[1] = (oc[1] + p0A * v0A.y) * rA2;
        oc[2] = (oc[2] + p0A * v0A.z) * rA2; oc[3] = (oc[3] + p0A * v0A.w) * rA2;
        oc[4] = (oc[4] + p0B * v0B.x) * rB2; oc[5] = (oc[5] + p0B * v0B.y) * rB2;
        oc[6] = (oc[6] + p0B * v0B.z) * rB2; oc[7] = (oc[7] + p0B * v0B.w) * rB2;
    }

    // out-projection (+ cattn_bo + cls residual via C), then folded cln2 + classifier
    float c8[8];
    {
        const bf16x8 boc = pack8(oc);
        f32x16 cc; CBIAS8(7, cc);
        const f32x16 dc = __builtin_amdgcn_mfma_f32_32x32x16_bf16(FRAG(10), boc, cc, 0, 0, 0);
#pragma unroll
        for (int r = 0; r < 8; r++) c8[r] = dc[r];
    }
    {
        float s = 0.f;
#pragma unroll
        for (int r = 0; r < 8; r++) s += c8[r];
        s = addxhalf(s);
        const float m = s * (1.0f / 16.0f);
        float vs = 0.f;
#pragma unroll
        for (int r = 0; r < 8; r++) { const float d = c8[r] - m; vs = fmaf(d, d, vs); }
        vs = addxhalf(vs);
        const float rstd = rsqrtf(vs * (1.0f / 16.0f) + EPS);
        const float nm = -m * rstd;
        const float4 wA = LD4(s_cw + 4 * hh), wB = LD4(s_cw + 8 + 4 * hh);
        float zp = 0.f;
        zp = fmaf(fmaf(c8[0], rstd, nm), wA.x, zp);
        zp = fmaf(fmaf(c8[1], rstd, nm), wA.y, zp);
        zp = fmaf(fmaf(c8[2], rstd, nm), wA.z, zp);
        zp = fmaf(fmaf(c8[3], rstd, nm), wA.w, zp);
        zp = fmaf(fmaf(c8[4], rstd, nm), wB.x, zp);
        zp = fmaf(fmaf(c8[5], rstd, nm), wB.y, zp);
        zp = fmaf(fmaf(c8[6], rstd, nm), wB.z, zp);
        zp = fmaf(fmaf(c8[7], rstd, nm), wB.w, zp);
        const float z = addxhalf(zp) + s_cw[16];
        const float sig = __builtin_amdgcn_rcpf(1.0f + ex2(-L2E * z));
        if (l == 0) out[b] = sig;
    }
}

extern "C" void kernel_launch(void* const* d_in, const int* in_sizes, int n_in,
                              void* d_out, int out_size, void* d_ws, size_t ws_size,
                              hipStream_t stream) {
    const float* x        = (const float*)d_in[0];
    const float* emb_w1   = (const float*)d_in[1];
    const float* emb_b1   = (const float*)d_in[2];
    const float* emb_w2   = (const float*)d_in[3];
    const float* emb_b2   = (const float*)d_in[4];
    const float* ln1_g    = (const float*)d_in[5];
    const float* ln1_b    = (const float*)d_in[6];
    const float* attn_wi  = (const float*)d_in[7];
    const float* attn_bi  = (const float*)d_in[8];
    const float* attn_wo  = (const float*)d_in[9];
    const float* attn_bo  = (const float*)d_in[10];
    const float* ln2_g    = (const float*)d_in[11];
    const float* ln2_b    = (const float*)d_in[12];
    const float* fc1_w    = (const float*)d_in[13];
    const float* fc1_b    = (const float*)d_in[14];
    const float* fc2_w    = (const float*)d_in[15];
    const float* fc2_b    = (const float*)d_in[16];
    const float* cls_tok  = (const float*)d_in[17];
    const float* cln1_g   = (const float*)d_in[18];
    const float* cln1_b   = (const float*)d_in[19];
    const float* cattn_wi = (const float*)d_in[20];
    const float* cattn_bi = (const float*)d_in[21];
    const float* cattn_wo = (const float*)d_in[22];
    const float* cattn_bo = (const float*)d_in[23];
    const float* cln2_g   = (const float*)d_in[24];
    const float* cln2_b   = (const float*)d_in[25];
    const float* clsfc_w  = (const float*)d_in[26];
    const float* clsfc_b  = (const float*)d_in[27];
    float* out = (float*)d_out;

    const int grid = BATCH / 4;   // 1 event per wave, 4 waves per block
    event_classifier_kernel<<<grid, 256, 0, stream>>>(
        x, emb_w1, emb_b1, emb_w2, emb_b2, ln1_g, ln1_b,
        attn_wi, attn_bi, attn_wo, attn_bo, ln2_g, ln2_b,
        fc1_w, fc1_b, fc2_w, fc2_b, cls_tok,
        cln1_g, cln1_b, cattn_wi, cattn_bi, cattn_wo, cattn_bo,
        cln2_g, cln2_b, clsfc_w, clsfc_b, out);
}